// Round 2
// baseline (111500.879 us; speedup 1.0000x reference)
//
#include <hip/hip_runtime.h>
#include <hip/hip_cooperative_groups.h>
#include <math.h>

namespace cg = cooperative_groups;

#define BATCH 512
#define TMAX  200
#define KIN   256
#define HID   1024

// LDS: union of A/B tile T[64][132] (8448 f) and C tiles Tc[4][64][68] (17408 f) + Pacc[256][17] (4352 f)
#define LDSF (4*4352 + 4*64*17)

__device__ __forceinline__ float sig_(float x) { return 1.0f / (1.0f + expf(-x)); }

__global__ __launch_bounds__(256, 1)
void kfused(const int* __restrict__ lengths,
            const float* __restrict__ eps,
            const float* __restrict__ W_ih, const float* __restrict__ b_ih,
            const float* __restrict__ b_hh,
            const float* __restrict__ W1a, const float* __restrict__ b1a,
            const float* __restrict__ W1b, const float* __restrict__ b1b,
            const float* __restrict__ W2a, const float* __restrict__ b2a,
            const float* __restrict__ W2b, const float* __restrict__ b2b,
            float* __restrict__ out_p1, float* __restrict__ out_p2, float* __restrict__ out_h,
            float* __restrict__ pbuf,      // [512][512]  p1|p2 of current step
            float* __restrict__ hbufT,     // [1024][512] h transposed
            float* __restrict__ habufT,    // [2048][512] tanh-hidden transposed (rows 0..1023 mlp1, 1024.. mlp2)
            float* __restrict__ stdbuf)    // [512][256]  exp(0.5*p2)
{
    __shared__ float lds[LDSF];
    __shared__ int sbs[TMAX], soff[TMAX];

    const int tid = threadIdx.x;
    const int bid = blockIdx.x;
    const int wv  = __builtin_amdgcn_readfirstlane(tid >> 6);
    const int l   = tid & 63;

    // packed-sequence tables, per block (no global exchange needed)
    if (tid < TMAX) {
        int c = 0;
        for (int b = 0; b < BATCH; ++b) c += (lengths[b] > tid) ? 1 : 0;
        sbs[tid] = c;
    }
    __syncthreads();
    if (tid == 0) { int a = 0; for (int i = 0; i < TMAX; ++i) { soff[i] = a; a += sbs[i]; } }
    __syncthreads();

    cg::grid_group grid = cg::this_grid();

    // A/B mapping: 4 batch-groups x 64 col-groups
    const int bg  = bid >> 6;            // 0..3   -> 128 batch rows
    const int cgA = bid & 63;            // 0..63
    const int bh  = wv & 1;              // batch half within 128
    const int ch  = wv >> 1;             // col half
    const int bAg = bg * 128 + bh * 64 + l;   // global batch row for A/B

    // C mapping: 8 batch-groups x 32 col-groups (64 batch x 16 cols), waves split K
    const int bbC = (bid >> 5) * 64;
    const int pcC = (bid & 31) * 16;
    const bool isP1 = (pcC < 256);
    const float* __restrict__ WbC = isP1 ? W1b : W2b;
    const int rowbC = isP1 ? pcC : (pcC - 256);
    const int acolC = isP1 ? 0 : HID;

    for (int t = 0; t < TMAX; ++t) {
        // ======================= phase A: x -> gi -> h =======================
        {
            const int jc0 = cgA * 16 + ch * 8;
            float accR[8] = {0.f,0.f,0.f,0.f,0.f,0.f,0.f,0.f};
            float accZ[8] = {0.f,0.f,0.f,0.f,0.f,0.f,0.f,0.f};
            float accN[8] = {0.f,0.f,0.f,0.f,0.f,0.f,0.f,0.f};

            if (t > 0) {
                const int bsp = sbs[t-1], ofp = soff[t-1];
                const float* __restrict__ epst = eps + (size_t)(t - 1) * (BATCH * KIN);
                for (int kc = 0; kc < 4; ++kc) {
                    const int kb = kc * 64;
                    // stage x[k][b] into T[64][132]; x = p1 + std * eps
                    #pragma unroll
                    for (int it = 0; it < 8; ++it) {
                        const int bq = (tid >> 4) + it * 16;      // 0..127 block-local batch
                        const int k4 = tid & 15;
                        const int kg = kb + k4 * 4;
                        const int bglob = bg * 128 + bq;
                        const float4 p1 = *(const float4*)&pbuf[(size_t)bglob * 512 + kg];
                        const float4 sd = *(const float4*)&stdbuf[(size_t)bglob * 256 + kg];
                        const float4 e  = *(const float4*)&epst[(size_t)bglob * KIN + kg];
                        lds[(k4*4+0)*132 + bq] = fmaf(sd.x, e.x, p1.x);
                        lds[(k4*4+1)*132 + bq] = fmaf(sd.y, e.y, p1.y);
                        lds[(k4*4+2)*132 + bq] = fmaf(sd.z, e.z, p1.z);
                        lds[(k4*4+3)*132 + bq] = fmaf(sd.w, e.w, p1.w);
                        if (cgA == 0 && bglob < bsp) {   // scatter p_{t-1} (once per batch-group)
                            const float4 p2 = *(const float4*)&pbuf[(size_t)bglob * 512 + 256 + kg];
                            *(float4*)&out_p1[(size_t)(ofp + bglob) * 256 + kg] = p1;
                            *(float4*)&out_p2[(size_t)(ofp + bglob) * 256 + kg] = p2;
                        }
                    }
                    __syncthreads();
                    #pragma unroll 4
                    for (int k4 = 0; k4 < 16; ++k4) {
                        const int kg = kb + k4 * 4;
                        const float a0 = lds[(k4*4+0)*132 + bh*64 + l];
                        const float a1 = lds[(k4*4+1)*132 + bh*64 + l];
                        const float a2 = lds[(k4*4+2)*132 + bh*64 + l];
                        const float a3 = lds[(k4*4+3)*132 + bh*64 + l];
                        #pragma unroll
                        for (int c = 0; c < 8; ++c) {
                            const int jg = jc0 + c;
                            const float4 wr = *(const float4*)&W_ih[(size_t)jg * KIN + kg];
                            const float4 wz = *(const float4*)&W_ih[(size_t)(HID + jg) * KIN + kg];
                            const float4 wn = *(const float4*)&W_ih[(size_t)(2*HID + jg) * KIN + kg];
                            accR[c] = fmaf(a3, wr.w, fmaf(a2, wr.z, fmaf(a1, wr.y, fmaf(a0, wr.x, accR[c]))));
                            accZ[c] = fmaf(a3, wz.w, fmaf(a2, wz.z, fmaf(a1, wz.y, fmaf(a0, wz.x, accZ[c]))));
                            accN[c] = fmaf(a3, wn.w, fmaf(a2, wn.z, fmaf(a1, wn.y, fmaf(a0, wn.x, accN[c]))));
                        }
                    }
                    __syncthreads();
                }
            }
            // GRU epilogue (h_prev = 0): write hbufT coalesced, stash h for hout bounce
            #pragma unroll
            for (int c = 0; c < 8; ++c) {
                const int jg = jc0 + c;
                const float r = sig_(accR[c] + b_ih[jg] + b_hh[jg]);
                const float z = sig_(accZ[c] + b_ih[HID + jg] + b_hh[HID + jg]);
                const float n = tanhf(accN[c] + b_ih[2*HID + jg] + r * b_hh[2*HID + jg]);
                const float h = (1.0f - z) * n;
                hbufT[(size_t)jg * 512 + bAg] = h;
                lds[(ch*8 + c)*132 + bh*64 + l] = h;
            }
            __syncthreads();
            // hout bounce: coalesced [N][1024] rows
            {
                const int bsz = sbs[t], ofs = soff[t];
                #pragma unroll
                for (int p = 0; p < 2; ++p) {
                    const int b  = (tid >> 2) + p * 64;      // 0..127
                    const int j4 = (tid & 3) * 4;
                    const int bglob = bg * 128 + b;
                    if (bglob < bsz) {
                        float4 v;
                        v.x = lds[(j4+0)*132 + b];
                        v.y = lds[(j4+1)*132 + b];
                        v.z = lds[(j4+2)*132 + b];
                        v.w = lds[(j4+3)*132 + b];
                        *(float4*)&out_h[(size_t)(ofs + bglob) * 1024 + cgA * 16 + j4] = v;
                    }
                }
            }
        }
        grid.sync();

        // ======================= phase B: ha = tanh(h @ Wa^T + b) =======================
        {
            const int nc0 = cgA * 32 + ch * 16;
            float acc[16] = {0.f,0.f,0.f,0.f,0.f,0.f,0.f,0.f,0.f,0.f,0.f,0.f,0.f,0.f,0.f,0.f};
            float4 pf[8];
            #pragma unroll
            for (int it = 0; it < 8; ++it) {
                const int k  = (tid >> 5) + it * 8;
                const int b4 = (tid & 31) * 4;
                pf[it] = *(const float4*)&hbufT[(size_t)k * 512 + bg * 128 + b4];
            }
            for (int kc = 0; kc < 16; ++kc) {
                __syncthreads();                   // previous compute done, T free
                #pragma unroll
                for (int it = 0; it < 8; ++it) {
                    const int k  = (tid >> 5) + it * 8;
                    const int b4 = (tid & 31) * 4;
                    *(float4*)&lds[k * 132 + b4] = pf[it];
                }
                __syncthreads();
                if (kc < 15) {                     // T14: issue next chunk's loads under compute
                    const int kb2 = (kc + 1) * 64;
                    #pragma unroll
                    for (int it = 0; it < 8; ++it) {
                        const int k  = (tid >> 5) + it * 8;
                        const int b4 = (tid & 31) * 4;
                        pf[it] = *(const float4*)&hbufT[(size_t)(kb2 + k) * 512 + bg * 128 + b4];
                    }
                }
                const int kb = kc * 64;
                #pragma unroll 4
                for (int k4 = 0; k4 < 16; ++k4) {
                    const float a0 = lds[(k4*4+0)*132 + bh*64 + l];
                    const float a1 = lds[(k4*4+1)*132 + bh*64 + l];
                    const float a2 = lds[(k4*4+2)*132 + bh*64 + l];
                    const float a3 = lds[(k4*4+3)*132 + bh*64 + l];
                    #pragma unroll
                    for (int c = 0; c < 16; ++c) {
                        const int n = nc0 + c;
                        const float* __restrict__ Wr = (n < HID) ? &W1a[(size_t)n * HID]
                                                                 : &W2a[(size_t)(n - HID) * HID];
                        const float4 w = *(const float4*)&Wr[kb + k4 * 4];
                        acc[c] = fmaf(a3, w.w, fmaf(a2, w.z, fmaf(a1, w.y, fmaf(a0, w.x, acc[c]))));
                    }
                }
            }
            #pragma unroll
            for (int c = 0; c < 16; ++c) {
                const int n = nc0 + c;
                const float bb = (n < HID) ? b1a[n] : b2a[n - HID];
                habufT[(size_t)n * 512 + bAg] = tanhf(acc[c] + bb);
            }
        }
        grid.sync();

        // ======================= phase C: p = ha @ Wb^T + b (wave K-split) =======================
        {
            float acc[16] = {0.f,0.f,0.f,0.f,0.f,0.f,0.f,0.f,0.f,0.f,0.f,0.f,0.f,0.f,0.f,0.f};
            for (int r = 0; r < 4; ++r) {
                #pragma unroll
                for (int it = 0; it < 16; ++it) {    // stage 4 chunks of 64k x 64b
                    const int q  = it >> 2;
                    const int k  = (tid >> 4) + (it & 3) * 16;
                    const int b4 = (tid & 15) * 4;
                    const int krow = acolC + (r * 4 + q) * 64 + k;
                    const float4 v = *(const float4*)&habufT[(size_t)krow * 512 + bbC + b4];
                    *(float4*)&lds[q * 4352 + k * 68 + b4] = v;
                }
                __syncthreads();
                const int kb = (r * 4 + wv) * 64;
                #pragma unroll 4
                for (int k4 = 0; k4 < 16; ++k4) {
                    const float a0 = lds[wv * 4352 + (k4*4+0)*68 + l];
                    const float a1 = lds[wv * 4352 + (k4*4+1)*68 + l];
                    const float a2 = lds[wv * 4352 + (k4*4+2)*68 + l];
                    const float a3 = lds[wv * 4352 + (k4*4+3)*68 + l];
                    #pragma unroll
                    for (int c = 0; c < 16; ++c) {
                        const float4 w = *(const float4*)&WbC[(size_t)(rowbC + c) * HID + kb + k4 * 4];
                        acc[c] = fmaf(a3, w.w, fmaf(a2, w.z, fmaf(a1, w.y, fmaf(a0, w.x, acc[c]))));
                    }
                }
                __syncthreads();
            }
            // deterministic cross-wave reduction via LDS
            float* Pacc = &lds[4 * 4352];
            #pragma unroll
            for (int c = 0; c < 16; ++c) Pacc[(wv * 64 + l) * 17 + c] = acc[c];
            __syncthreads();
            {
                const int b  = tid >> 2;             // 0..63
                const int c4 = (tid & 3) * 4;
                float s[4];
                #pragma unroll
                for (int i = 0; i < 4; ++i) {
                    const float sum = Pacc[(0*64 + b)*17 + c4 + i] + Pacc[(1*64 + b)*17 + c4 + i]
                                    + Pacc[(2*64 + b)*17 + c4 + i] + Pacc[(3*64 + b)*17 + c4 + i];
                    const int pg = pcC + c4 + i;
                    const float bias = isP1 ? b1b[pg] : b2b[pg - 256];
                    s[i] = sum + bias;
                }
                *(float4*)&pbuf[(size_t)(bbC + b) * 512 + pcC + c4] = make_float4(s[0], s[1], s[2], s[3]);
                if (!isP1) {   // std = exp(0.5*p2), computed once instead of 64x in A-staging
                    float4 sd = make_float4(expf(0.5f*s[0]), expf(0.5f*s[1]), expf(0.5f*s[2]), expf(0.5f*s[3]));
                    *(float4*)&stdbuf[(size_t)(bbC + b) * 256 + (pcC - 256) + c4] = sd;
                }
            }
        }
        grid.sync();
    }

    // final scatter of p_199
    {
        const int bsz = sbs[TMAX-1], ofs = soff[TMAX-1];
        const int total = bsz * 512;
        const int idx0 = (bid * 256 + tid) * 4;
        const int stride = 256 * 256 * 4;
        for (int i = idx0; i < total; i += stride) {
            const int b = i >> 9, c = i & 511;
            const float4 v = *(const float4*)&pbuf[(size_t)b * 512 + c];
            if (c < 256) *(float4*)&out_p1[(size_t)(ofs + b) * 256 + c] = v;
            else         *(float4*)&out_p2[(size_t)(ofs + b) * 256 + (c - 256)] = v;
        }
    }
}

extern "C" void kernel_launch(void* const* d_in, const int* in_sizes, int n_in,
                              void* d_out, int out_size, void* d_ws, size_t ws_size,
                              hipStream_t stream)
{
    (void)in_sizes; (void)n_in; (void)ws_size;
    const int*   lengths = (const int*)  d_in[1];
    const float* eps     = (const float*)d_in[2];
    const float* W_ih    = (const float*)d_in[5];
    const float* b_ih    = (const float*)d_in[6];
    const float* b_hh    = (const float*)d_in[8];
    const float* W1a     = (const float*)d_in[9];
    const float* b1a     = (const float*)d_in[10];
    const float* W1b     = (const float*)d_in[11];
    const float* b1b     = (const float*)d_in[12];
    const float* W2a     = (const float*)d_in[13];
    const float* b2a     = (const float*)d_in[14];
    const float* W2b     = (const float*)d_in[15];
    const float* b2b     = (const float*)d_in[16];

    float* out = (float*)d_out;
    const size_t N = (size_t)out_size / 1536;
    float* out_p1 = out;
    float* out_p2 = out + N * 256;
    float* out_h  = out + N * 512;

    float* pbuf   = (float*)d_ws;            // 512*512
    float* hbufT  = pbuf  + 512 * 512;       // 1024*512
    float* habufT = hbufT + 1024 * 512;      // 2048*512
    float* stdbuf = habufT + 2048 * 512;     // 512*256   (total ~7.9 MB)

    void* args[] = {
        (void*)&lengths, (void*)&eps, (void*)&W_ih, (void*)&b_ih, (void*)&b_hh,
        (void*)&W1a, (void*)&b1a, (void*)&W1b, (void*)&b1b,
        (void*)&W2a, (void*)&b2a, (void*)&W2b, (void*)&b2b,
        (void*)&out_p1, (void*)&out_p2, (void*)&out_h,
        (void*)&pbuf, (void*)&hbufT, (void*)&habufT, (void*)&stdbuf
    };
    hipLaunchCooperativeKernel((void*)kfused, dim3(256), dim3(256), args, 0, stream);
}

// Round 3
// 59325.122 us; speedup vs baseline: 1.8795x; 1.8795x over previous
//
#include <hip/hip_runtime.h>
#include <hip/hip_cooperative_groups.h>
#include <math.h>

namespace cg = cooperative_groups;

#define TMAX  200
#define BLKS  512

__device__ __forceinline__ float sig_(float x) { return 1.0f / (1.0f + expf(-x)); }
__device__ __forceinline__ float4 fma4(float s, float4 v, float4 a) {
    a.x = fmaf(s, v.x, a.x); a.y = fmaf(s, v.y, a.y);
    a.z = fmaf(s, v.z, a.z); a.w = fmaf(s, v.w, a.w);
    return a;
}

// Layouts (all k-major in ws, written/read only by vector ops):
//   xT  [256][512]   x_t transposed      (written by phase C of t-1)
//   hT  [1024][512]  h transposed        (A -> B)
//   haT [2048][512]  tanh-hidden transp. (B -> C; rows 0..1023 mlp1, 1024.. mlp2)
//   pT  [512][512]   p transposed        (rows 0..255 p1, 256..511 p2)
// Weights/biases are consumed straight from d_in (read-only -> scalar loads safe).

__global__ __launch_bounds__(256, 2)
void kfused(const int* __restrict__ lengths,
            const float* __restrict__ eps,
            const float* __restrict__ W_ih, const float* __restrict__ b_ih,
            const float* __restrict__ b_hh,
            const float* __restrict__ W1a, const float* __restrict__ b1a,
            const float* __restrict__ W1b, const float* __restrict__ b1b,
            const float* __restrict__ W2a, const float* __restrict__ b2a,
            const float* __restrict__ W2b, const float* __restrict__ b2b,
            float* __restrict__ out_p1, float* __restrict__ out_p2, float* __restrict__ out_h,
            float* __restrict__ pT, float* __restrict__ hT,
            float* __restrict__ haT, float* __restrict__ xT)
{
    __shared__ float lds[8192];          // 32 KB, reused per phase
    __shared__ int sbs[TMAX], soff[TMAX];

    const int tid  = threadIdx.x;
    const int bid  = blockIdx.x;
    const int wv   = __builtin_amdgcn_readfirstlane(tid >> 6);
    const int lane = tid & 63;
    const int bg   = bid & 1;            // batch half (256 each)
    const int grp  = bid >> 1;           // 0..255
    const int b0   = bg * 256 + lane * 4;

    if (tid < TMAX) {
        int c = 0;
        for (int b = 0; b < 512; ++b) c += (lengths[b] > tid) ? 1 : 0;
        sbs[tid] = c;
    }
    __syncthreads();
    if (tid == 0) { int a = 0; for (int i = 0; i < TMAX; ++i) { soff[i] = a; a += sbs[i]; } }
    __syncthreads();

    cg::grid_group grid = cg::this_grid();

    for (int t = 0; t < TMAX; ++t) {
        // ---- scatter p_{t-1} rows (coalesced via LDS transpose), 32 blocks ----
        if (t > 0 && bid < 32) {
            const int bbase = bid * 16;
            const int bsp = sbs[t-1], ofp = soff[t-1];
            #pragma unroll
            for (int it = 0; it < 8; ++it) {            // load pT[512 c][16 b] tile
                const int c = it * 64 + (tid >> 2);
                const int f = (tid & 3) * 4;
                *(float4*)&lds[c * 16 + f] = *(const float4*)&pT[c * 512 + bbase + f];
            }
            __syncthreads();
            {
                const int b = tid >> 4, ct = tid & 15;
                if (bbase + b < bsp) {
                    const size_t row = (size_t)(ofp + bbase + b);
                    #pragma unroll
                    for (int i = 0; i < 8; ++i) {
                        const int c = i * 64 + ct * 4;
                        float4 v = { lds[(c+0)*16 + b], lds[(c+1)*16 + b],
                                     lds[(c+2)*16 + b], lds[(c+3)*16 + b] };
                        if (c < 256) *(float4*)&out_p1[row * 256 + c] = v;
                        else         *(float4*)&out_p2[row * 256 + (c - 256)] = v;
                    }
                }
            }
            __syncthreads();
        }

        // ================= phase A: gi = x@W_ih^T -> h (full K in-wave) =================
        {
            const int j = grp * 4 + wv;                  // 0..1023
            float4 aR = {0,0,0,0}, aZ = {0,0,0,0}, aN = {0,0,0,0};
            if (t > 0) {
                for (int k = 0; k < 256; k += 4) {
                    const float4 x0 = *(const float4*)&xT[(k+0) * 512 + b0];
                    const float4 x1 = *(const float4*)&xT[(k+1) * 512 + b0];
                    const float4 x2 = *(const float4*)&xT[(k+2) * 512 + b0];
                    const float4 x3 = *(const float4*)&xT[(k+3) * 512 + b0];
                    const float4 wr = *(const float4*)&W_ih[(size_t)j * 256 + k];
                    const float4 wz = *(const float4*)&W_ih[(size_t)(j + 1024) * 256 + k];
                    const float4 wn = *(const float4*)&W_ih[(size_t)(j + 2048) * 256 + k];
                    aR = fma4(wr.x, x0, fma4(wr.y, x1, fma4(wr.z, x2, fma4(wr.w, x3, aR))));
                    aZ = fma4(wz.x, x0, fma4(wz.y, x1, fma4(wz.z, x2, fma4(wz.w, x3, aZ))));
                    aN = fma4(wn.x, x0, fma4(wn.y, x1, fma4(wn.z, x2, fma4(wn.w, x3, aN))));
                }
            }
            const float br = b_ih[j] + b_hh[j];
            const float bz = b_ih[j + 1024] + b_hh[j + 2048 - 1024];
            const float bn = b_ih[j + 2048];
            const float gn = b_hh[j + 2048];
            float4 h;
            {
                float r0 = sig_(aR.x + br), r1 = sig_(aR.y + br), r2 = sig_(aR.z + br), r3 = sig_(aR.w + br);
                float z0 = sig_(aZ.x + bz), z1 = sig_(aZ.y + bz), z2 = sig_(aZ.z + bz), z3 = sig_(aZ.w + bz);
                h.x = (1.f - z0) * tanhf(aN.x + bn + r0 * gn);
                h.y = (1.f - z1) * tanhf(aN.y + bn + r1 * gn);
                h.z = (1.f - z2) * tanhf(aN.z + bn + r2 * gn);
                h.w = (1.f - z3) * tanhf(aN.w + bn + r3 * gn);
            }
            *(float4*)&hT[(size_t)j * 512 + b0] = h;
            *(float4*)&lds[wv * 260 + lane * 4] = h;     // bounce for out_h
            __syncthreads();
            {
                const int bsz = sbs[t], ofs = soff[t];
                const int bglob = bg * 256 + tid;        // tid indexes 256 local batches
                if (bglob < bsz) {
                    float4 v = { lds[0*260 + tid], lds[1*260 + tid],
                                 lds[2*260 + tid], lds[3*260 + tid] };
                    *(float4*)&out_h[(size_t)(ofs + bglob) * 1024 + grp * 4] = v;
                }
            }
        }
        grid.sync();

        // ================= phase B: ha = tanh(h @ Wa^T + ba), K-split 4 =================
        {
            const int n0 = grp * 8;                      // 0..2047
            const float* __restrict__ Wa; const float* __restrict__ ba; int nr;
            if (n0 < 1024) { Wa = W1a; ba = b1a; nr = n0; }
            else           { Wa = W2a; ba = b2a; nr = n0 - 1024; }
            const int k0 = wv * 256;
            float4 acc[8];
            #pragma unroll
            for (int n = 0; n < 8; ++n) acc[n] = make_float4(0.f, 0.f, 0.f, 0.f);
            for (int k = k0; k < k0 + 256; k += 4) {
                const float4 h0 = *(const float4*)&hT[(size_t)(k+0) * 512 + b0];
                const float4 h1 = *(const float4*)&hT[(size_t)(k+1) * 512 + b0];
                const float4 h2 = *(const float4*)&hT[(size_t)(k+2) * 512 + b0];
                const float4 h3 = *(const float4*)&hT[(size_t)(k+3) * 512 + b0];
                #pragma unroll
                for (int n = 0; n < 8; ++n) {
                    const float4 w = *(const float4*)&Wa[(size_t)(nr + n) * 1024 + k];
                    acc[n] = fma4(w.x, h0, fma4(w.y, h1, fma4(w.z, h2, fma4(w.w, h3, acc[n]))));
                }
            }
            #pragma unroll
            for (int n = 0; n < 8; ++n)
                *(float4*)&lds[wv * 2048 + n * 256 + lane * 4] = acc[n];
            __syncthreads();
            {
                const int n = tid >> 5, b8 = (tid & 31) * 8;
                const float bias = ba[nr + n];
                #pragma unroll
                for (int hh = 0; hh < 8; hh += 4) {
                    float4 s = *(const float4*)&lds[0*2048 + n*256 + b8 + hh];
                    #pragma unroll
                    for (int w = 1; w < 4; ++w) {
                        const float4 p = *(const float4*)&lds[w*2048 + n*256 + b8 + hh];
                        s.x += p.x; s.y += p.y; s.z += p.z; s.w += p.w;
                    }
                    s.x = tanhf(s.x + bias); s.y = tanhf(s.y + bias);
                    s.z = tanhf(s.z + bias); s.w = tanhf(s.w + bias);
                    *(float4*)&haT[(size_t)(n0 + n) * 512 + bg * 256 + b8 + hh] = s;
                }
            }
            __syncthreads();
        }
        grid.sync();

        // ====== phase C: p = ha @ Wb^T + bb; fuse x_{t+1} = p1 + exp(.5 p2)*eps[t] ======
        {
            const int c = grp;                           // 0..255 (col pair c, c+256)
            const int k0 = wv * 256;
            float4 a1 = {0,0,0,0}, a2 = {0,0,0,0};
            for (int k = k0; k < k0 + 256; k += 4) {
                const float4 u0 = *(const float4*)&haT[(size_t)(k+0) * 512 + b0];
                const float4 u1 = *(const float4*)&haT[(size_t)(k+1) * 512 + b0];
                const float4 u2 = *(const float4*)&haT[(size_t)(k+2) * 512 + b0];
                const float4 u3 = *(const float4*)&haT[(size_t)(k+3) * 512 + b0];
                const float4 v0 = *(const float4*)&haT[(size_t)(1024 + k+0) * 512 + b0];
                const float4 v1 = *(const float4*)&haT[(size_t)(1024 + k+1) * 512 + b0];
                const float4 v2 = *(const float4*)&haT[(size_t)(1024 + k+2) * 512 + b0];
                const float4 v3 = *(const float4*)&haT[(size_t)(1024 + k+3) * 512 + b0];
                const float4 w1 = *(const float4*)&W1b[(size_t)c * 1024 + k];
                const float4 w2 = *(const float4*)&W2b[(size_t)c * 1024 + k];
                a1 = fma4(w1.x, u0, fma4(w1.y, u1, fma4(w1.z, u2, fma4(w1.w, u3, a1))));
                a2 = fma4(w2.x, v0, fma4(w2.y, v1, fma4(w2.z, v2, fma4(w2.w, v3, a2))));
            }
            *(float4*)&lds[(wv * 2 + 0) * 256 + lane * 4] = a1;
            *(float4*)&lds[(wv * 2 + 1) * 256 + lane * 4] = a2;
            __syncthreads();
            {
                float p1 = 0.f, p2 = 0.f;
                #pragma unroll
                for (int w = 0; w < 4; ++w) {
                    p1 += lds[(w * 2 + 0) * 256 + tid];
                    p2 += lds[(w * 2 + 1) * 256 + tid];
                }
                p1 += b1b[c]; p2 += b2b[c];
                const int bglob = bg * 256 + tid;
                pT[(size_t)c * 512 + bglob] = p1;
                pT[(size_t)(c + 256) * 512 + bglob] = p2;
                const float e = eps[(size_t)t * 512 * 256 + (size_t)bglob * 256 + c];
                xT[(size_t)c * 512 + bglob] = fmaf(expf(0.5f * p2), e, p1);
            }
            __syncthreads();
        }
        grid.sync();
    }

    // ---- final scatter of p_199 ----
    {
        const int bsl = sbs[TMAX-1], ofl = soff[TMAX-1];
        if (bid < bsl) {
            const int b = bid;
            const float v1 = pT[(size_t)tid * 512 + b];
            const float v2 = pT[(size_t)(tid + 256) * 512 + b];
            out_p1[(size_t)(ofl + b) * 256 + tid] = v1;
            out_p2[(size_t)(ofl + b) * 256 + tid] = v2;
        }
    }
}

extern "C" void kernel_launch(void* const* d_in, const int* in_sizes, int n_in,
                              void* d_out, int out_size, void* d_ws, size_t ws_size,
                              hipStream_t stream)
{
    (void)in_sizes; (void)n_in; (void)ws_size;
    const int*   lengths = (const int*)  d_in[1];
    const float* eps     = (const float*)d_in[2];
    const float* W_ih    = (const float*)d_in[5];
    const float* b_ih    = (const float*)d_in[6];
    const float* b_hh    = (const float*)d_in[8];
    const float* W1a     = (const float*)d_in[9];
    const float* b1a     = (const float*)d_in[10];
    const float* W1b     = (const float*)d_in[11];
    const float* b1b     = (const float*)d_in[12];
    const float* W2a     = (const float*)d_in[13];
    const float* b2a     = (const float*)d_in[14];
    const float* W2b     = (const float*)d_in[15];
    const float* b2b     = (const float*)d_in[16];

    float* out = (float*)d_out;
    const size_t N = (size_t)out_size / 1536;
    float* out_p1 = out;
    float* out_p2 = out + N * 256;
    float* out_h  = out + N * 512;

    float* pT  = (float*)d_ws;            // [512][512]
    float* hT  = pT  + 512 * 512;         // [1024][512]
    float* haT = hT  + 1024 * 512;        // [2048][512]
    float* xT  = haT + 2048 * 512;        // [256][512]   total ~7.9 MB

    void* args[] = {
        (void*)&lengths, (void*)&eps, (void*)&W_ih, (void*)&b_ih, (void*)&b_hh,
        (void*)&W1a, (void*)&b1a, (void*)&W1b, (void*)&b1b,
        (void*)&W2a, (void*)&b2a, (void*)&W2b, (void*)&b2b,
        (void*)&out_p1, (void*)&out_p2, (void*)&out_h,
        (void*)&pT, (void*)&hT, (void*)&haT, (void*)&xT
    };
    hipLaunchCooperativeKernel((void*)kfused, dim3(BLKS), dim3(256), args, 0, stream);
}